// Round 5
// baseline (324.175 us; speedup 1.0000x reference)
//
#include <hip/hip_runtime.h>
#include <cmath>

#define WIN 11
#define HALO 5
#define IMG 512
#define TW 64
#define TH 16
#define RH (TH + 2*HALO)   /* 26 h-blurred rows per tile */
#define SH2 72             /* h-buffer row stride in halves: 144B, 16B-aligned */
#define NIMG 48            /* 16 batch * 3 channels */
#define NPIX (16.0 * 3.0 * 512.0 * 512.0)

typedef _Float16 f16;
typedef _Float16 h2 __attribute__((ext_vector_type(2)));

struct GaussW { float w[WIN]; };

__device__ __forceinline__ unsigned pk2(float a, float b) {
    auto h = __builtin_amdgcn_cvt_pkrtz(a, b);   // __fp16 ext_vector(2)
    return __builtin_bit_cast(unsigned, h);
}

__global__ void __launch_bounds__(64) zero_kernel(float* out) {
    if (threadIdx.x == 0) out[0] = 0.f;
}

// One block = one 64x16 output tile. Stage A: 208 threads h-blur 26 rows
// (8 outputs each, f32 math) -> f16 LDS buffers. Stage B: packed-f16
// vertical blur (2x2 patch/thread) + SSIM + reduce.
__global__ void __launch_bounds__(256) ssim_tile_kernel(
        const float* __restrict__ xin, const float* __restrict__ yin,
        float* __restrict__ out_acc, GaussW W) {
    __shared__ __align__(16) f16 hb[5][RH * SH2];
    __shared__ float wsum[4];

    const int tid = threadIdx.x;
    const int bx = blockIdx.x, by = blockIdx.y;
    const size_t ibase = (size_t)blockIdx.z * (IMG * IMG);
    const float* __restrict__ xb = xin + ibase;
    const float* __restrict__ yb = yin + ibase;

    // ---- Stage A: horizontal blur of 5 fields, 8 outputs/thread.
    if (tid < RH * (TW / 8)) {
        const int r  = tid >> 3;          // 0..25
        const int cg = tid & 7;           // 0..7
        const int gy  = by * TH - HALO + r;
        const int gx0 = bx * TW - HALO + cg * 8;   // window cols gx0..gx0+17

        float xv[18], yv[18];
        const float* xr = xb + (size_t)gy * IMG;
        const float* yr = yb + (size_t)gy * IMG;
        const bool interior = (bx >= 1 && bx <= 6 && by >= 1 && by <= 30);
        if (interior) {
            // gx0 == 3 (mod 4): aligned float4 runs cover [gx0+1, gx0+16]
            xv[0] = xr[gx0];  yv[0] = yr[gx0];
            #pragma unroll
            for (int q = 0; q < 4; ++q) {
                float4 a = *(const float4*)(xr + gx0 + 1 + 4*q);
                float4 b = *(const float4*)(yr + gx0 + 1 + 4*q);
                xv[1+4*q] = a.x; xv[2+4*q] = a.y; xv[3+4*q] = a.z; xv[4+4*q] = a.w;
                yv[1+4*q] = b.x; yv[2+4*q] = b.y; yv[3+4*q] = b.z; yv[4+4*q] = b.w;
            }
            xv[17] = xr[gx0 + 17];  yv[17] = yr[gx0 + 17];
        } else {
            const bool rowok = ((unsigned)gy < IMG);
            #pragma unroll
            for (int j = 0; j < 18; ++j) {
                int gx = gx0 + j;
                bool ok = rowok && ((unsigned)gx < IMG);
                xv[j] = ok ? xr[gx] : 0.f;
                yv[j] = ok ? yr[gx] : 0.f;
            }
        }

        float ax[8]  = {0,0,0,0,0,0,0,0}, ay[8]  = {0,0,0,0,0,0,0,0};
        float axx[8] = {0,0,0,0,0,0,0,0}, ayy[8] = {0,0,0,0,0,0,0,0};
        float axy[8] = {0,0,0,0,0,0,0,0};

        // accumulate-by-input: each input element's products computed ONCE
        #pragma unroll
        for (int j = 0; j < 18; ++j) {
            float xs = xv[j], ys = yv[j];
            float xx = xs * xs, yy = ys * ys, xy = xs * ys;
            #pragma unroll
            for (int o = 0; o < 8; ++o) {
                int k = j - o;                 // tap index, const after unroll
                if (k >= 0 && k < WIN) {
                    float wk = W.w[k];
                    ax[o]  += wk * xs;
                    ay[o]  += wk * ys;
                    axx[o] += wk * xx;
                    ayy[o] += wk * yy;
                    axy[o] += wk * xy;
                }
            }
        }

        const int ob = r * SH2 + cg * 8;     // halves; byte off = 144r+16cg, 16B-aligned
        {
            uint4 u;
            u.x = pk2(ax[0],  ax[1]);  u.y = pk2(ax[2],  ax[3]);
            u.z = pk2(ax[4],  ax[5]);  u.w = pk2(ax[6],  ax[7]);
            *(uint4*)&hb[0][ob] = u;
            u.x = pk2(ay[0],  ay[1]);  u.y = pk2(ay[2],  ay[3]);
            u.z = pk2(ay[4],  ay[5]);  u.w = pk2(ay[6],  ay[7]);
            *(uint4*)&hb[1][ob] = u;
            u.x = pk2(axx[0], axx[1]); u.y = pk2(axx[2], axx[3]);
            u.z = pk2(axx[4], axx[5]); u.w = pk2(axx[6], axx[7]);
            *(uint4*)&hb[2][ob] = u;
            u.x = pk2(ayy[0], ayy[1]); u.y = pk2(ayy[2], ayy[3]);
            u.z = pk2(ayy[4], ayy[5]); u.w = pk2(ayy[6], ayy[7]);
            *(uint4*)&hb[3][ob] = u;
            u.x = pk2(axy[0], axy[1]); u.y = pk2(axy[2], axy[3]);
            u.z = pk2(axy[4], axy[5]); u.w = pk2(axy[6], axy[7]);
            *(uint4*)&hb[4][ob] = u;
        }
    }
    __syncthreads();

    // ---- Stage B: packed-f16 vertical blur; each thread owns a 2x2 patch
    // (cols 2*c2, 2*c2+1; rows r0, r0+1), reading 12 f16x2 rows per field.
    const int c2 = tid & 31;          // col pair 0..31
    const int r0 = (tid >> 5) << 1;   // 0,2,...,14
    const int hbase = 2 * c2;         // half index within a row

    h2 w2[WIN];
    #pragma unroll
    for (int k = 0; k < WIN; ++k) {
        f16 wk = (f16)W.w[k];
        w2[k] = (h2){wk, wk};
    }

    h2 acc[5][2];
    #pragma unroll
    for (int f = 0; f < 5; ++f) {
        acc[f][0] = (h2){(f16)0, (f16)0};
        acc[f][1] = (h2){(f16)0, (f16)0};
    }

    #pragma unroll
    for (int f = 0; f < 5; ++f) {
        const f16* buf = hb[f];
        h2 v[12];
        #pragma unroll
        for (int k = 0; k < 12; ++k)
            v[k] = *(const h2*)&buf[(r0 + k) * SH2 + hbase];
        #pragma unroll
        for (int k = 0; k < WIN; ++k) {
            acc[f][0] += w2[k] * v[k];
            acc[f][1] += w2[k] * v[k + 1];
        }
    }

    const float C1 = 0.01f * 0.01f;
    const float C2 = 0.03f * 0.03f;
    float local = 0.f;
    #pragma unroll
    for (int o = 0; o < 2; ++o) {
        #pragma unroll
        for (int h = 0; h < 2; ++h) {
            float mux = (float)acc[0][o][h];
            float muy = (float)acc[1][o][h];
            float exx = (float)acc[2][o][h];
            float eyy = (float)acc[3][o][h];
            float exy = (float)acc[4][o][h];
            float mux2 = mux * mux, muy2 = muy * muy, muxy = mux * muy;
            float sxx_ = exx - mux2;
            float syy_ = eyy - muy2;
            float sxy_ = exy - muxy;
            float num = (2.f * muxy + C1) * (2.f * sxy_ + C2);
            float den = (mux2 + muy2 + C1) * (sxx_ + syy_ + C2);
            local += num * __builtin_amdgcn_rcpf(den + 1e-8f);
        }
    }

    // ---- block reduce: wave shuffle, then one atomic per block
    #pragma unroll
    for (int off = 32; off > 0; off >>= 1)
        local += __shfl_down(local, off, 64);
    if ((tid & 63) == 0) wsum[tid >> 6] = local;
    __syncthreads();
    if (tid == 0)
        atomicAdd(out_acc, wsum[0] + wsum[1] + wsum[2] + wsum[3]);
}

__global__ void __launch_bounds__(64) finish_kernel(float* out) {
    if (threadIdx.x == 0)
        out[0] = 1.0f - out[0] * (float)(1.0 / NPIX);
}

extern "C" void kernel_launch(void* const* d_in, const int* in_sizes, int n_in,
                              void* d_out, int out_size, void* d_ws, size_t ws_size,
                              hipStream_t stream) {
    const float* x = (const float*)d_in[0];
    const float* y = (const float*)d_in[1];
    float* out = (float*)d_out;

    GaussW gw;
    double g[WIN], s = 0.0;
    for (int i = 0; i < WIN; ++i) {
        double d = (double)(i - WIN / 2);
        g[i] = exp(-(d * d) / (2.0 * 1.5 * 1.5));
        s += g[i];
    }
    for (int i = 0; i < WIN; ++i) gw.w[i] = (float)(g[i] / s);

    hipLaunchKernelGGL(zero_kernel, dim3(1), dim3(64), 0, stream, out);
    dim3 grid(IMG / TW, IMG / TH, NIMG);
    hipLaunchKernelGGL(ssim_tile_kernel, grid, dim3(256), 0, stream, x, y, out, gw);
    hipLaunchKernelGGL(finish_kernel, dim3(1), dim3(64), 0, stream, out);
}

// Round 6
// 230.802 us; speedup vs baseline: 1.4046x; 1.4046x over previous
//
#include <hip/hip_runtime.h>
#include <cmath>
#include <utility>

#define WIN 11
#define HALO 5
#define IMG 512
#define TW 64
#define TH 16
#define RH (TH + 2*HALO)
#define SH2 72
#define NIMG 48
#define NPIX (16.0 * 3.0 * 512.0 * 512.0)

typedef _Float16 f16;
typedef _Float16 h2 __attribute__((ext_vector_type(2)));

struct GaussW { float w[WIN]; };

__device__ __forceinline__ unsigned pk2(float a, float b) {
    auto h = __builtin_amdgcn_cvt_pkrtz(a, b);   // __fp16 ext_vector(2)
    return __builtin_bit_cast(unsigned, h);
}

__global__ void __launch_bounds__(64) zero_kernel(float* out) {
    if (threadIdx.x == 0) out[0] = 0.f;
}

__global__ void __launch_bounds__(64) finish_kernel(float* out) {
    if (threadIdx.x == 0)
        out[0] = 1.0f - out[0] * (float)(1.0 / NPIX);
}

// ---------------- K1: horizontal blur of 5 fields -> f16 workspace ----------
// ws layout: ws[(f*chunkN + lz)*IMG*IMG + row*IMG + col], f16.
// One wave = one image row (64 col-groups of 8). No LDS, no barrier.
__global__ void __launch_bounds__(256, 1) k1_hblur(
        const float* __restrict__ xin, const float* __restrict__ yin,
        f16* __restrict__ ws, int imgOff, int chunkN, GaussW W) {
    const int tid = threadIdx.x;
    const int c   = tid & 63;                    // out cols 8c..8c+7
    const int row = blockIdx.y * 4 + (tid >> 6);
    const int lz  = blockIdx.z;
    const size_t rbase = ((size_t)(imgOff + lz) * IMG + row) * IMG;
    const float* xr = xin + rbase;
    const float* yr = yin + rbase;
    const int gx0 = c * 8 - 5;                   // window cols gx0..gx0+17

    float xv[18], yv[18];
    if (c >= 1 && c <= 62) {
        // gx0+1 = 8c-4 is 4-aligned: aligned float4 runs cover [gx0+1, gx0+16]
        xv[0] = xr[gx0];  yv[0] = yr[gx0];
        #pragma unroll
        for (int q = 0; q < 4; ++q) {
            float4 a = *(const float4*)(xr + gx0 + 1 + 4*q);
            float4 b = *(const float4*)(yr + gx0 + 1 + 4*q);
            xv[1+4*q] = a.x; xv[2+4*q] = a.y; xv[3+4*q] = a.z; xv[4+4*q] = a.w;
            yv[1+4*q] = b.x; yv[2+4*q] = b.y; yv[3+4*q] = b.z; yv[4+4*q] = b.w;
        }
        xv[17] = xr[gx0 + 17];  yv[17] = yr[gx0 + 17];
    } else {
        #pragma unroll
        for (int j = 0; j < 18; ++j) {
            int gx = gx0 + j;
            bool ok = ((unsigned)gx < IMG);
            xv[j] = ok ? xr[gx] : 0.f;
            yv[j] = ok ? yr[gx] : 0.f;
        }
    }

    float ax[8]  = {0,0,0,0,0,0,0,0}, ay[8]  = {0,0,0,0,0,0,0,0};
    float axx[8] = {0,0,0,0,0,0,0,0}, ayy[8] = {0,0,0,0,0,0,0,0};
    float axy[8] = {0,0,0,0,0,0,0,0};
    #pragma unroll
    for (int j = 0; j < 18; ++j) {
        float xs = xv[j], ys = yv[j];
        float xx = xs * xs, yy = ys * ys, xy = xs * ys;
        #pragma unroll
        for (int o = 0; o < 8; ++o) {
            int k = j - o;
            if (k >= 0 && k < WIN) {
                float wk = W.w[k];
                ax[o]  += wk * xs;
                ay[o]  += wk * ys;
                axx[o] += wk * xx;
                ayy[o] += wk * yy;
                axy[o] += wk * xy;
            }
        }
    }

    const size_t fstride = (size_t)chunkN * (IMG * IMG);
    const size_t ob = (size_t)lz * (IMG * IMG) + (size_t)row * IMG + c * 8;
    uint4 u;
    u.x = pk2(ax[0],  ax[1]);  u.y = pk2(ax[2],  ax[3]);
    u.z = pk2(ax[4],  ax[5]);  u.w = pk2(ax[6],  ax[7]);
    *(uint4*)&ws[ob] = u;
    u.x = pk2(ay[0],  ay[1]);  u.y = pk2(ay[2],  ay[3]);
    u.z = pk2(ay[4],  ay[5]);  u.w = pk2(ay[6],  ay[7]);
    *(uint4*)&ws[ob + fstride] = u;
    u.x = pk2(axx[0], axx[1]); u.y = pk2(axx[2], axx[3]);
    u.z = pk2(axx[4], axx[5]); u.w = pk2(axx[6], axx[7]);
    *(uint4*)&ws[ob + 2*fstride] = u;
    u.x = pk2(ayy[0], ayy[1]); u.y = pk2(ayy[2], ayy[3]);
    u.z = pk2(ayy[4], ayy[5]); u.w = pk2(ayy[6], ayy[7]);
    *(uint4*)&ws[ob + 3*fstride] = u;
    u.x = pk2(axy[0], axy[1]); u.y = pk2(axy[2], axy[3]);
    u.z = pk2(axy[4], axy[5]); u.w = pk2(axy[6], axy[7]);
    *(uint4*)&ws[ob + 4*fstride] = u;
}

// ---------------- K2: vertical blur + SSIM + reduce -------------------------
// Thread owns one f16x2 column-pair over a 16-row strip. No LDS, no barrier.
__global__ void __launch_bounds__(256, 1) k2_vblur(
        const f16* __restrict__ ws, float* __restrict__ out_acc,
        int chunkN, GaussW W) {
    const int tid = threadIdx.x;                 // col-pair 0..255
    const int r0  = blockIdx.y * TH;
    const int lz  = blockIdx.z;
    const unsigned* base0 = (const unsigned*)ws;
    const size_t fstride = (size_t)chunkN * (IMG * IMG / 2);   // uints per field
    const size_t ibase   = (size_t)lz * (IMG * IMG / 2) + tid;

    h2 w2[WIN];
    #pragma unroll
    for (int k = 0; k < WIN; ++k) {
        f16 wk = (f16)W.w[k];
        w2[k] = (h2){wk, wk};
    }

    h2 acc[5][TH];
    #pragma unroll
    for (int f = 0; f < 5; ++f)
        #pragma unroll
        for (int o = 0; o < TH; ++o) acc[f][o] = (h2){(f16)0, (f16)0};

    auto run = [&](auto guard_c) {
        constexpr bool G = decltype(guard_c)::value;
        #pragma unroll
        for (int f = 0; f < 5; ++f) {
            const unsigned* bp = base0 + f * fstride + ibase;
            #pragma unroll
            for (int j = 0; j < TH + 2*HALO; ++j) {
                int r = r0 - HALO + j;
                unsigned uv = 0;
                if (!G || (unsigned)r < IMG) uv = bp[(size_t)r * (IMG/2)];
                h2 v = __builtin_bit_cast(h2, uv);
                #pragma unroll
                for (int o = 0; o < TH; ++o) {
                    int k = j - o;
                    if (k >= 0 && k < WIN) acc[f][o] += w2[k] * v;
                }
            }
        }
    };
    if (blockIdx.y >= 1 && blockIdx.y <= (IMG/TH - 2))
        run(std::integral_constant<bool, false>{});
    else
        run(std::integral_constant<bool, true>{});

    const float C1 = 0.01f * 0.01f;
    const float C2 = 0.03f * 0.03f;
    float local = 0.f;
    #pragma unroll
    for (int o = 0; o < TH; ++o) {
        #pragma unroll
        for (int h = 0; h < 2; ++h) {
            float mux = (float)acc[0][o][h];
            float muy = (float)acc[1][o][h];
            float exx = (float)acc[2][o][h];
            float eyy = (float)acc[3][o][h];
            float exy = (float)acc[4][o][h];
            float mux2 = mux * mux, muy2 = muy * muy, muxy = mux * muy;
            float sxx_ = exx - mux2;
            float syy_ = eyy - muy2;
            float sxy_ = exy - muxy;
            float num = (2.f * muxy + C1) * (2.f * sxy_ + C2);
            float den = (mux2 + muy2 + C1) * (sxx_ + syy_ + C2);
            local += num * __builtin_amdgcn_rcpf(den + 1e-8f);
        }
    }

    #pragma unroll
    for (int off = 32; off > 0; off >>= 1)
        local += __shfl_down(local, off, 64);
    if ((tid & 63) == 0) atomicAdd(out_acc, local);
}

// ---------------- Fallback (R4 kernel): used only if ws is too small --------
__global__ void __launch_bounds__(256) fb_tile_kernel(
        const float* __restrict__ xin, const float* __restrict__ yin,
        float* __restrict__ out_acc, GaussW W) {
    __shared__ __align__(16) f16 hb[5][RH * SH2];
    __shared__ float wsum[4];
    const int tid = threadIdx.x;
    const int bx = blockIdx.x, by = blockIdx.y;
    const size_t ibase = (size_t)blockIdx.z * (IMG * IMG);
    const float* __restrict__ xb = xin + ibase;
    const float* __restrict__ yb = yin + ibase;

    if (tid < RH * (TW / 8)) {
        const int r  = tid >> 3;
        const int cg = tid & 7;
        const int gy  = by * TH - HALO + r;
        const int gx0 = bx * TW - HALO + cg * 8;
        float xv[18], yv[18];
        const float* xr = xb + (size_t)gy * IMG;
        const float* yr = yb + (size_t)gy * IMG;
        const bool interior = (bx >= 1 && bx <= 6 && by >= 1 && by <= 30);
        if (interior) {
            xv[0] = xr[gx0];  yv[0] = yr[gx0];
            #pragma unroll
            for (int q = 0; q < 4; ++q) {
                float4 a = *(const float4*)(xr + gx0 + 1 + 4*q);
                float4 b = *(const float4*)(yr + gx0 + 1 + 4*q);
                xv[1+4*q] = a.x; xv[2+4*q] = a.y; xv[3+4*q] = a.z; xv[4+4*q] = a.w;
                yv[1+4*q] = b.x; yv[2+4*q] = b.y; yv[3+4*q] = b.z; yv[4+4*q] = b.w;
            }
            xv[17] = xr[gx0 + 17];  yv[17] = yr[gx0 + 17];
        } else {
            const bool rowok = ((unsigned)gy < IMG);
            #pragma unroll
            for (int j = 0; j < 18; ++j) {
                int gx = gx0 + j;
                bool ok = rowok && ((unsigned)gx < IMG);
                xv[j] = ok ? xr[gx] : 0.f;
                yv[j] = ok ? yr[gx] : 0.f;
            }
        }
        float ax[8]={0,0,0,0,0,0,0,0}, ay[8]={0,0,0,0,0,0,0,0};
        float axx[8]={0,0,0,0,0,0,0,0}, ayy[8]={0,0,0,0,0,0,0,0}, axy[8]={0,0,0,0,0,0,0,0};
        #pragma unroll
        for (int j = 0; j < 18; ++j) {
            float xs = xv[j], ys = yv[j];
            float xx = xs*xs, yy = ys*ys, xy = xs*ys;
            #pragma unroll
            for (int o = 0; o < 8; ++o) {
                int k = j - o;
                if (k >= 0 && k < WIN) {
                    float wk = W.w[k];
                    ax[o]+=wk*xs; ay[o]+=wk*ys; axx[o]+=wk*xx; ayy[o]+=wk*yy; axy[o]+=wk*xy;
                }
            }
        }
        const int ob = r * SH2 + cg * 8;
        uint4 u;
        u.x=pk2(ax[0],ax[1]); u.y=pk2(ax[2],ax[3]); u.z=pk2(ax[4],ax[5]); u.w=pk2(ax[6],ax[7]);
        *(uint4*)&hb[0][ob] = u;
        u.x=pk2(ay[0],ay[1]); u.y=pk2(ay[2],ay[3]); u.z=pk2(ay[4],ay[5]); u.w=pk2(ay[6],ay[7]);
        *(uint4*)&hb[1][ob] = u;
        u.x=pk2(axx[0],axx[1]); u.y=pk2(axx[2],axx[3]); u.z=pk2(axx[4],axx[5]); u.w=pk2(axx[6],axx[7]);
        *(uint4*)&hb[2][ob] = u;
        u.x=pk2(ayy[0],ayy[1]); u.y=pk2(ayy[2],ayy[3]); u.z=pk2(ayy[4],ayy[5]); u.w=pk2(ayy[6],ayy[7]);
        *(uint4*)&hb[3][ob] = u;
        u.x=pk2(axy[0],axy[1]); u.y=pk2(axy[2],axy[3]); u.z=pk2(axy[4],axy[5]); u.w=pk2(axy[6],axy[7]);
        *(uint4*)&hb[4][ob] = u;
    }
    __syncthreads();

    const int c2 = tid & 31;
    const int r0 = (tid >> 5) << 1;
    const int hbase = 2 * c2;
    h2 w2[WIN];
    #pragma unroll
    for (int k = 0; k < WIN; ++k) { f16 wk = (f16)W.w[k]; w2[k] = (h2){wk, wk}; }
    h2 acc[5][2];
    #pragma unroll
    for (int f = 0; f < 5; ++f) { acc[f][0]=(h2){(f16)0,(f16)0}; acc[f][1]=(h2){(f16)0,(f16)0}; }
    #pragma unroll
    for (int f = 0; f < 5; ++f) {
        const f16* buf = hb[f];
        h2 v[12];
        #pragma unroll
        for (int k = 0; k < 12; ++k) v[k] = *(const h2*)&buf[(r0 + k) * SH2 + hbase];
        #pragma unroll
        for (int k = 0; k < WIN; ++k) { acc[f][0] += w2[k]*v[k]; acc[f][1] += w2[k]*v[k+1]; }
    }
    const float C1 = 0.01f * 0.01f;
    const float C2 = 0.03f * 0.03f;
    float local = 0.f;
    #pragma unroll
    for (int o = 0; o < 2; ++o)
        #pragma unroll
        for (int h = 0; h < 2; ++h) {
            float mux=(float)acc[0][o][h], muy=(float)acc[1][o][h];
            float exx=(float)acc[2][o][h], eyy=(float)acc[3][o][h], exy=(float)acc[4][o][h];
            float mux2=mux*mux, muy2=muy*muy, muxy=mux*muy;
            float num=(2.f*muxy+C1)*(2.f*(exy-muxy)+C2);
            float den=(mux2+muy2+C1)*((exx-mux2)+(eyy-muy2)+C2);
            local += num * __builtin_amdgcn_rcpf(den + 1e-8f);
        }
    #pragma unroll
    for (int off = 32; off > 0; off >>= 1) local += __shfl_down(local, off, 64);
    if ((tid & 63) == 0) wsum[tid >> 6] = local;
    __syncthreads();
    if (tid == 0) atomicAdd(out_acc, wsum[0]+wsum[1]+wsum[2]+wsum[3]);
}

extern "C" void kernel_launch(void* const* d_in, const int* in_sizes, int n_in,
                              void* d_out, int out_size, void* d_ws, size_t ws_size,
                              hipStream_t stream) {
    const float* x = (const float*)d_in[0];
    const float* y = (const float*)d_in[1];
    float* out = (float*)d_out;

    GaussW gw;
    double g[WIN], s = 0.0;
    for (int i = 0; i < WIN; ++i) {
        double d = (double)(i - WIN / 2);
        g[i] = exp(-(d * d) / (2.0 * 1.5 * 1.5));
        s += g[i];
    }
    for (int i = 0; i < WIN; ++i) gw.w[i] = (float)(g[i] / s);

    hipLaunchKernelGGL(zero_kernel, dim3(1), dim3(64), 0, stream, out);

    auto need = [](int n) { return (size_t)5 * n * IMG * IMG * sizeof(f16); };
    int chunk = NIMG;                       // 48 -> 24 -> 12 -> 6 -> 3
    while (chunk > 3 && need(chunk) > ws_size) chunk >>= 1;

    if (need(chunk) <= ws_size) {
        f16* ws = (f16*)d_ws;
        for (int off = 0; off < NIMG; off += chunk) {
            hipLaunchKernelGGL(k1_hblur, dim3(1, IMG/4, chunk), dim3(256), 0, stream,
                               x, y, ws, off, chunk, gw);
            hipLaunchKernelGGL(k2_vblur, dim3(1, IMG/TH, chunk), dim3(256), 0, stream,
                               ws, out, chunk, gw);
        }
    } else {
        hipLaunchKernelGGL(fb_tile_kernel, dim3(IMG/TW, IMG/TH, NIMG), dim3(256),
                           0, stream, x, y, out, gw);
    }

    hipLaunchKernelGGL(finish_kernel, dim3(1), dim3(64), 0, stream, out);
}